// Round 5
// baseline (150.540 us; speedup 1.0000x reference)
//
#include <hip/hip_runtime.h>

// CompoundClassifier, round 12: MEASUREMENT ROUND #2 (precompute path).
// Base = r11 (best, 112.0us). Known: edge ~28-30us (r10), fill ~46us.
// Unknown: pq_gemm + cvt_w + gaps = ~38us residual. This round: pq_gemm and
// cvt_w each run their (idempotent) bodies PQ_REP/CVT_REP=5 times with a
// memory-clobber per rep (prevents load/math hoisting). dur ~= 112 + 4*(pq+cvt).
// If pq is slow its top-5 counter row diagnoses why (VALU vs HBM vs occupancy).
// Edge kernel identical to r11.

#define H  128
#define NI 20000
#define NC 10000
#define NE 1000000

#define PQ_REP  5
#define CVT_REP 5

typedef _Float16 half8   __attribute__((ext_vector_type(8)));
typedef float    floatx2 __attribute__((ext_vector_type(2)));
typedef float    floatx4 __attribute__((ext_vector_type(4)));

// ws byte layout
#define P8_OFF    0
#define Q8_OFF    (NI * H)                    // 2,560,000
#define WFRAG_B   ((NI + NC) * H)             // 3,840,000 (16B aligned)
// WFRAG: W1 as f16 in MFMA B-fragment order, 64 KB:
//   flat = ((isQ*8 + w*2+nt)*4 + ks)*512 + lane*8 + j
//   holds W1[k][n], k = isQ*128 + ks*32 + (lane>>4)*8 + j,
//                   n = (w)*32 + nt*16 + (lane&15)         (w*2+nt = ntw)

#define PB (NI / 16)   // 1250
#define QB (NC / 16)   // 625

// ---------- fp8 e4m3 helpers (HW path on gfx950; SW fallback for safety) ----
#if __has_builtin(__builtin_amdgcn_cvt_pk_f32_fp8) && __has_builtin(__builtin_amdgcn_cvt_pk_fp8_f32)
#define HW_FP8 1
#else
#define HW_FP8 0
__device__ inline unsigned char enc_e4m3(float x) {
    unsigned s = x < 0.0f ? 0x80u : 0u;
    float a = fminf(fabsf(x), 448.0f);
    if (a < 0.0009765625f) return (unsigned char)s;       // < 2^-10 -> 0
    int e; float m = frexpf(a, &e);                       // a = m*2^e, m in [0.5,1)
    int E = e + 6;                                        // biased exp
    if (E <= 0) {                                         // subnormal: f*2^-9
        int f = (int)rintf(a * 512.0f);
        if (f > 7) return (unsigned char)(s | 0x08);
        return (unsigned char)(s | f);
    }
    int f = (int)rintf((m * 2.0f - 1.0f) * 8.0f);
    if (f == 8) { f = 0; ++E; }
    if (E > 15 || (E == 15 && f > 6)) { E = 15; f = 6; }  // clamp to 448
    return (unsigned char)(s | (E << 3) | f);
}
__device__ inline float dec_e4m3(unsigned char b) {
    int E = (b >> 3) & 15, f = b & 7;
    float v = (E == 0) ? (float)f * 0.001953125f          // f * 2^-9
                       : (float)(8 + f) * exp2f((float)(E - 10));
    return (b & 0x80) ? -v : v;
}
#endif

__device__ inline floatx2 relu2(floatx2 v) {
#if __has_builtin(__builtin_elementwise_max)
    floatx2 z = {0.0f, 0.0f};
    return __builtin_elementwise_max(v, z);
#else
    floatx2 r = { fmaxf(v.x, 0.0f), fmaxf(v.y, 0.0f) };
    return r;
#endif
}

__device__ __forceinline__ float fast_sigmoid(float x) {
#if __has_builtin(__builtin_amdgcn_exp2f) && __has_builtin(__builtin_amdgcn_rcpf)
    const float t = __builtin_amdgcn_exp2f(-1.4426950408889634f * x);
    return __builtin_amdgcn_rcpf(1.0f + t);
#else
    return 1.0f / (1.0f + __expf(-x));
#endif
}

// ---------- one-shot: W1 -> f16 fragment-ordered table (x CVT_REP) ----------
__launch_bounds__(256)
__global__ void cvt_w(const float* __restrict__ W1,   // [256][128] row-major
                      unsigned char* __restrict__ wsb) {
#pragma unroll 1
    for (int rep = 0; rep < CVT_REP; ++rep) {
        asm volatile("" ::: "memory");   // force re-execution each rep
        const int flat = blockIdx.x * 256 + threadIdx.x;   // over 32768
        const int j    = flat & 7;
        const int lane = (flat >> 3) & 63;
        const int ks   = (flat >> 9) & 3;
        const int ntw  = (flat >> 11) & 7;
        const int isQ  = (flat >> 14) & 1;
        const int n = (ntw >> 1) * 32 + (ntw & 1) * 16 + (lane & 15);
        const int k = isQ * 128 + ks * 32 + (lane >> 4) * 8 + j;
        ((_Float16*)(wsb + WFRAG_B))[flat] = (_Float16)W1[k * H + n];
    }
}

// ---------- P/Q precompute: 16x16x32 f16 MFMA, fp8 epilogue (x PQ_REP) ------
__launch_bounds__(256)
__global__ void pq_gemm(const float* __restrict__ xin,
                        const float* __restrict__ xcmp,
                        const float* __restrict__ b1,
                        unsigned char* __restrict__ wsb) {
#pragma unroll 1
    for (int rep = 0; rep < PQ_REP; ++rep) {
        asm volatile("" ::: "memory");   // force re-execution each rep
        const int b    = blockIdx.x;
        const bool isQ = (b >= PB);
        const int  rb  = (isQ ? b - PB : b) * 16;
        const float* X = isQ ? xcmp : xin;
        unsigned char* OUT8 = wsb + (isQ ? Q8_OFF : P8_OFF);
        const _Float16* wfrag = (const _Float16*)(wsb + WFRAG_B);

        const int lane = threadIdx.x & 63;
        const int w    = threadIdx.x >> 6;
        const int quad = lane >> 4;
        const int m    = lane & 15;

        // B-fragments: lane-contiguous b128 from the fragment-ordered table
        half8 bf[2][4];
        float b1v[2];
#pragma unroll
        for (int nt = 0; nt < 2; ++nt) {
            const int ntw = w * 2 + nt;
#pragma unroll
            for (int ks = 0; ks < 4; ++ks)
                bf[nt][ks] = *(const half8*)(wfrag + (((isQ ? 8 : 0) + ntw) * 4 + ks) * 512 + lane * 8);
            const int n = w * 32 + nt * 16 + m;
            b1v[nt] = isQ ? b1[n] : 0.0f;
        }

        // A-fragments: row rb+m, contiguous 8 floats -> half8
        half8 af[4];
        const float* xr = X + (long)(rb + m) * H + quad * 8;
#pragma unroll
        for (int ks = 0; ks < 4; ++ks) {
            float4 a = *(const float4*)(xr + ks * 32);
            float4 c = *(const float4*)(xr + ks * 32 + 4);
            half8 v = { (_Float16)a.x, (_Float16)a.y, (_Float16)a.z, (_Float16)a.w,
                        (_Float16)c.x, (_Float16)c.y, (_Float16)c.z, (_Float16)c.w };
            af[ks] = v;
        }

        floatx4 acc[2] = { (floatx4)0.0f, (floatx4)0.0f };
#pragma unroll
        for (int ks = 0; ks < 4; ++ks)
#pragma unroll
            for (int nt = 0; nt < 2; ++nt)
                acc[nt] = __builtin_amdgcn_mfma_f32_16x16x32_f16(af[ks], bf[nt][ks], acc[nt], 0, 0, 0);

        // epilogue: +b1, encode fp8, byte stores
        // C/D: col = lane&15 within n-tile, row = quad*4 + r
#pragma unroll
        for (int nt = 0; nt < 2; ++nt) {
            const int col = w * 32 + nt * 16 + m;
#pragma unroll
            for (int r = 0; r < 4; ++r) {
                const float v = acc[nt][r] + b1v[nt];
#if HW_FP8
                const unsigned u = (unsigned)__builtin_amdgcn_cvt_pk_fp8_f32(v, v, 0, false);
                OUT8[(rb + quad * 4 + r) * H + col] = (unsigned char)(u & 0xff);
#else
                OUT8[(rb + quad * 4 + r) * H + col] = enc_e4m3(v);
#endif
            }
        }
    }
}

// ---------- edge kernel: 8 lanes/edge, branch-free 16-pass, unroll-2 ----------
// (identical to r11)
#define EGRID 2048
#define ESTEP (32 * EGRID)          // 65536 edges per device pass
// NE = 1,000,000 = 15 full passes (k=0..14) + tail pass k=15 (16,960 edges)

__launch_bounds__(256)
__global__ void edge_mlp(const unsigned char* __restrict__ wsb,
                         const int* __restrict__ src_idx,
                         const int* __restrict__ dst_idx,
                         const float* __restrict__ W2,
                         const float* __restrict__ b2p,
                         float* __restrict__ out) {
    const int tid  = threadIdx.x;
    const int c    = tid & 7;       // 16-byte slice of the 128-B row
    const int slot = tid >> 3;      // edge within block-pass (0..31)

    // W2 slice: 16 floats for cols c*16..c*16+15 (regs, reused 16 passes)
    floatx2 w2v[8];
#pragma unroll
    for (int i = 0; i < 8; ++i) w2v[i] = *(const floatx2*)(W2 + c * 16 + i * 2);
    const float b2v = b2p[0];

    const unsigned char* P8 = wsb + P8_OFF;
    const unsigned char* Q8 = wsb + Q8_OFF;
    const int ebase = blockIdx.x * 32 + slot;   // < 65536

#define LDIDX(K, SI, DI) do {                                        \
        int _e = ebase + (K) * ESTEP;                                \
        _e = _e < NE ? _e : NE - 1;                                  \
        SI = __builtin_nontemporal_load(src_idx + _e);               \
        DI = __builtin_nontemporal_load(dst_idx + _e);               \
    } while (0)

#define GATHER(SI, DI, PD, QD) do {                                  \
        PD = *(const uint4*)(P8 + (SI) * H + c * 16);                \
        QD = *(const uint4*)(Q8 + (DI) * H + c * 16);                \
    } while (0)

#define COMPUTE(K, PD, QD, MASKED) do {                              \
        floatx2 acc2 = {0.0f, 0.0f};                                 \
        const unsigned pw[4] = { PD.x, PD.y, PD.z, PD.w };           \
        const unsigned qw[4] = { QD.x, QD.y, QD.z, QD.w };           \
        _Pragma("unroll")                                            \
        for (int jw = 0; jw < 4; ++jw) {                             \
            floatx2 pl, ph, ql, qh;                                  \
            DECODE(pw[jw], qw[jw], pl, ph, ql, qh);                  \
            acc2 += relu2(pl + ql) * w2v[2 * jw];                    \
            acc2 += relu2(ph + qh) * w2v[2 * jw + 1];                \
        }                                                            \
        float acc = acc2.x + acc2.y;                                 \
        acc += __shfl_xor(acc, 1);                                   \
        acc += __shfl_xor(acc, 2);                                   \
        acc += __shfl_xor(acc, 4);                                   \
        const int _e = ebase + (K) * ESTEP;                          \
        if (c == 0 && (!(MASKED) || _e < NE)) {                      \
            const float r = fast_sigmoid(acc + b2v);                 \
            __builtin_nontemporal_store(r, out + _e);                \
        }                                                            \
    } while (0)

#if HW_FP8
#define DECODE(PW, QW, PL, PH, QL, QH) do {                          \
        PL = __builtin_amdgcn_cvt_pk_f32_fp8((int)(PW), false);      \
        PH = __builtin_amdgcn_cvt_pk_f32_fp8((int)(PW), true);       \
        QL = __builtin_amdgcn_cvt_pk_f32_fp8((int)(QW), false);      \
        QH = __builtin_amdgcn_cvt_pk_f32_fp8((int)(QW), true);       \
    } while (0)
#else
#define DECODE(PW, QW, PL, PH, QL, QH) do {                          \
        PL = { dec_e4m3((PW) & 0xff), dec_e4m3(((PW) >> 8) & 0xff) };  \
        PH = { dec_e4m3(((PW) >> 16) & 0xff), dec_e4m3((PW) >> 24) };  \
        QL = { dec_e4m3((QW) & 0xff), dec_e4m3(((QW) >> 8) & 0xff) };  \
        QH = { dec_e4m3(((QW) >> 16) & 0xff), dec_e4m3((QW) >> 24) };  \
    } while (0)
#endif

    // ---- prologue: rows(0,1) + idx(2,3) in flight ----
    int siA, diA, siB, diB, si2, di2, si3, di3;
    uint4 pdA, qdA, pdB, qdB;
    LDIDX(0, siA, diA);
    LDIDX(1, siB, diB);
    GATHER(siA, diA, pdA, qdA);
    GATHER(siB, diB, pdB, qdB);
    LDIDX(2, si2, di2);
    LDIDX(3, si3, di3);

    // ---- main: 7 iterations x 2 passes = k 0..13 (all full) ----
#pragma unroll 1
    for (int i = 0; i < 7; ++i) {
        const int k = 2 * i;
        uint4 pdC, qdC, pdD, qdD;
        GATHER(si2, di2, pdC, qdC);          // rows k+2
        GATHER(si3, di3, pdD, qdD);          // rows k+3
        LDIDX(k + 4, si2, di2);              // idx k+4 (clamped; k+4<=17)
        LDIDX(k + 5, si3, di3);              // idx k+5
        COMPUTE(k,     pdA, qdA, false);
        COMPUTE(k + 1, pdB, qdB, false);
        pdA = pdC; qdA = qdC; pdB = pdD; qdB = qdD;
    }

    // ---- epilogue: k=14 (full), k=15 (tail, store-masked) ----
    COMPUTE(14, pdA, qdA, false);
    COMPUTE(15, pdB, qdB, true);

#undef LDIDX
#undef GATHER
#undef COMPUTE
#undef DECODE
}

extern "C" void kernel_launch(void* const* d_in, const int* in_sizes, int n_in,
                              void* d_out, int out_size, void* d_ws, size_t ws_size,
                              hipStream_t stream) {
    const float* xin  = (const float*)d_in[0];
    const float* xcmp = (const float*)d_in[1];
    const int*   eidx = (const int*)d_in[2];    // [2,E]: first E src, next E dst
    const float* W1   = (const float*)d_in[3];
    const float* b1   = (const float*)d_in[4];
    const float* W2   = (const float*)d_in[5];
    const float* b2   = (const float*)d_in[6];
    float* out = (float*)d_out;
    unsigned char* wsb = (unsigned char*)d_ws;  // ~3.9 MB used

    hipLaunchKernelGGL(cvt_w,   dim3(128),     dim3(256), 0, stream, W1, wsb);
    hipLaunchKernelGGL(pq_gemm, dim3(PB + QB), dim3(256), 0, stream, xin, xcmp, b1, wsb);
    hipLaunchKernelGGL(edge_mlp, dim3(EGRID),  dim3(256), 0, stream,
                       wsb, eidx, eidx + NE, W2, b2, out);
}

// Round 6
// 110.206 us; speedup vs baseline: 1.3660x; 1.3660x over previous
//
#include <hip/hip_runtime.h>

// CompoundClassifier, round 13: multi-strip pq_gemm (amortize the latency chain).
//   P = x_ing @ W1[:128], Q = x_cmp @ W1[128:] + b1  -> stored as fp8 (1 B/el)
//   out[e] = sigmoid( relu(P[s]+Q[d]) . W2 + b2 )
// r12 measurement: pq_gemm single ~15-18us, ALL pipes idle (VALU 9%, Mfma 3%,
// HBM 3%, Occ 30%) -> latency-bound: 1875 tiny blocks each re-loading its
// 32KB B-fragment slice from L2 (60MB total) for only 8 MFMAs.
// r13: 470 blocks (313 P + 157 Q), each does 4 consecutive 16-row strips:
// bf/b1 loaded ONCE per block (wfrag traffic /4), A-fragments for strip s+1
// prefetched during strip s compute (ping-pong regs, full unroll). Edge (r11)
// and cvt_w untouched. Budget: fill~46 fixed + edge~28.6 + pq(17->~6) + cvt~2.

#define H  128
#define NI 20000
#define NC 10000
#define NE 1000000

typedef _Float16 half8   __attribute__((ext_vector_type(8)));
typedef float    floatx2 __attribute__((ext_vector_type(2)));
typedef float    floatx4 __attribute__((ext_vector_type(4)));

// ws byte layout
#define P8_OFF    0
#define Q8_OFF    (NI * H)                    // 2,560,000
#define WFRAG_B   ((NI + NC) * H)             // 3,840,000 (16B aligned)
// WFRAG: W1 as f16 in MFMA B-fragment order, 64 KB:
//   flat = ((isQ*8 + w*2+nt)*4 + ks)*512 + lane*8 + j
//   holds W1[k][n], k = isQ*128 + ks*32 + (lane>>4)*8 + j,
//                   n = (w)*32 + nt*16 + (lane&15)         (w*2+nt = ntw)

#define PB (NI / 16)   // 1250 strips of P
#define QB (NC / 16)   // 625 strips of Q
#define NSTRIP 4
#define PBLKS ((PB + NSTRIP - 1) / NSTRIP)    // 313
#define QBLKS ((QB + NSTRIP - 1) / NSTRIP)    // 157

// ---------- fp8 e4m3 helpers (HW path on gfx950; SW fallback for safety) ----
#if __has_builtin(__builtin_amdgcn_cvt_pk_f32_fp8) && __has_builtin(__builtin_amdgcn_cvt_pk_fp8_f32)
#define HW_FP8 1
#else
#define HW_FP8 0
__device__ inline unsigned char enc_e4m3(float x) {
    unsigned s = x < 0.0f ? 0x80u : 0u;
    float a = fminf(fabsf(x), 448.0f);
    if (a < 0.0009765625f) return (unsigned char)s;       // < 2^-10 -> 0
    int e; float m = frexpf(a, &e);                       // a = m*2^e, m in [0.5,1)
    int E = e + 6;                                        // biased exp
    if (E <= 0) {                                         // subnormal: f*2^-9
        int f = (int)rintf(a * 512.0f);
        if (f > 7) return (unsigned char)(s | 0x08);
        return (unsigned char)(s | f);
    }
    int f = (int)rintf((m * 2.0f - 1.0f) * 8.0f);
    if (f == 8) { f = 0; ++E; }
    if (E > 15 || (E == 15 && f > 6)) { E = 15; f = 6; }  // clamp to 448
    return (unsigned char)(s | (E << 3) | f);
}
__device__ inline float dec_e4m3(unsigned char b) {
    int E = (b >> 3) & 15, f = b & 7;
    float v = (E == 0) ? (float)f * 0.001953125f          // f * 2^-9
                       : (float)(8 + f) * exp2f((float)(E - 10));
    return (b & 0x80) ? -v : v;
}
#endif

__device__ inline floatx2 relu2(floatx2 v) {
#if __has_builtin(__builtin_elementwise_max)
    floatx2 z = {0.0f, 0.0f};
    return __builtin_elementwise_max(v, z);
#else
    floatx2 r = { fmaxf(v.x, 0.0f), fmaxf(v.y, 0.0f) };
    return r;
#endif
}

__device__ __forceinline__ float fast_sigmoid(float x) {
#if __has_builtin(__builtin_amdgcn_exp2f) && __has_builtin(__builtin_amdgcn_rcpf)
    const float t = __builtin_amdgcn_exp2f(-1.4426950408889634f * x);
    return __builtin_amdgcn_rcpf(1.0f + t);
#else
    return 1.0f / (1.0f + __expf(-x));
#endif
}

// ---------- one-shot: W1 -> f16 fragment-ordered table ----------
__launch_bounds__(256)
__global__ void cvt_w(const float* __restrict__ W1,   // [256][128] row-major
                      unsigned char* __restrict__ wsb) {
    const int flat = blockIdx.x * 256 + threadIdx.x;   // over 32768
    const int j    = flat & 7;
    const int lane = (flat >> 3) & 63;
    const int ks   = (flat >> 9) & 3;
    const int ntw  = (flat >> 11) & 7;
    const int isQ  = (flat >> 14) & 1;
    const int n = (ntw >> 1) * 32 + (ntw & 1) * 16 + (lane & 15);
    const int k = isQ * 128 + ks * 32 + (lane >> 4) * 8 + j;
    ((_Float16*)(wsb + WFRAG_B))[flat] = (_Float16)W1[k * H + n];
}

// ---------- P/Q precompute: 16x16x32 f16 MFMA, 4 strips/block ----------
__launch_bounds__(256)
__global__ void pq_gemm(const float* __restrict__ xin,
                        const float* __restrict__ xcmp,
                        const float* __restrict__ b1,
                        unsigned char* __restrict__ wsb) {
    const int b    = blockIdx.x;
    const bool isQ = (b >= PBLKS);
    const int  sb  = isQ ? b - PBLKS : b;
    const int  s0  = sb * NSTRIP;                 // first strip of this block
    const int  smax = (isQ ? QB : PB) - 1;        // last valid strip
    const float* X = isQ ? xcmp : xin;
    unsigned char* OUT8 = wsb + (isQ ? Q8_OFF : P8_OFF);
    const _Float16* wfrag = (const _Float16*)(wsb + WFRAG_B);

    const int lane = threadIdx.x & 63;
    const int w    = threadIdx.x >> 6;
    const int quad = lane >> 4;
    const int m    = lane & 15;

    // B-fragments + bias: loaded ONCE, reused for all strips
    half8 bf[2][4];
    float b1v[2];
#pragma unroll
    for (int nt = 0; nt < 2; ++nt) {
        const int ntw = w * 2 + nt;
#pragma unroll
        for (int ks = 0; ks < 4; ++ks)
            bf[nt][ks] = *(const half8*)(wfrag + (((isQ ? 8 : 0) + ntw) * 4 + ks) * 512 + lane * 8);
        const int n = w * 32 + nt * 16 + m;
        b1v[nt] = isQ ? b1[n] : 0.0f;
    }

    // A-fragment loader for strip S (clamped -> always in-bounds)
#define LOADA(S, AF) do {                                                \
        const int _s = (S) > smax ? smax : (S);                          \
        const float* xr = X + (long)(_s * 16 + m) * H + quad * 8;        \
        _Pragma("unroll")                                                \
        for (int ks = 0; ks < 4; ++ks) {                                 \
            float4 a = *(const float4*)(xr + ks * 32);                   \
            float4 c = *(const float4*)(xr + ks * 32 + 4);               \
            half8 v = { (_Float16)a.x, (_Float16)a.y, (_Float16)a.z,     \
                        (_Float16)a.w, (_Float16)c.x, (_Float16)c.y,     \
                        (_Float16)c.z, (_Float16)c.w };                  \
            AF[ks] = v;                                                  \
        }                                                                \
    } while (0)

    // compute + fp8 epilogue for strip S from fragments AF
#define STRIPC(S, AF) do {                                               \
        floatx4 acc[2] = { (floatx4)0.0f, (floatx4)0.0f };               \
        _Pragma("unroll")                                                \
        for (int ks = 0; ks < 4; ++ks)                                   \
            _Pragma("unroll")                                            \
            for (int nt = 0; nt < 2; ++nt)                               \
                acc[nt] = __builtin_amdgcn_mfma_f32_16x16x32_f16(        \
                              AF[ks], bf[nt][ks], acc[nt], 0, 0, 0);     \
        if ((S) <= smax) {                                               \
            const int rb = (S) * 16;                                     \
            _Pragma("unroll")                                            \
            for (int nt = 0; nt < 2; ++nt) {                             \
                const int col = w * 32 + nt * 16 + m;                    \
                _Pragma("unroll")                                        \
                for (int r = 0; r < 4; ++r) {                            \
                    const float v = acc[nt][r] + b1v[nt];                \
                    EMIT8(OUT8 + (rb + quad * 4 + r) * H + col, v);      \
                }                                                        \
            }                                                            \
        }                                                                \
    } while (0)

#if HW_FP8
#define EMIT8(PTR, V) do {                                               \
        const unsigned _u = (unsigned)__builtin_amdgcn_cvt_pk_fp8_f32((V), (V), 0, false); \
        *(unsigned char*)(PTR) = (unsigned char)(_u & 0xff);             \
    } while (0)
#else
#define EMIT8(PTR, V) do { *(unsigned char*)(PTR) = enc_e4m3(V); } while (0)
#endif

    // ping-pong A fragments: prefetch strip s+1 before computing strip s
    half8 afA[4], afB[4];
    LOADA(s0, afA);
    LOADA(s0 + 1, afB);
    STRIPC(s0,     afA);
    LOADA(s0 + 2, afA);
    STRIPC(s0 + 1, afB);
    LOADA(s0 + 3, afB);
    STRIPC(s0 + 2, afA);
    STRIPC(s0 + 3, afB);

#undef LOADA
#undef STRIPC
#undef EMIT8
}

// ---------- edge kernel: 8 lanes/edge, branch-free 16-pass, unroll-2 ----------
// (identical to r11, best measured)
#define EGRID 2048
#define ESTEP (32 * EGRID)          // 65536 edges per device pass
// NE = 1,000,000 = 15 full passes (k=0..14) + tail pass k=15 (16,960 edges)

__launch_bounds__(256)
__global__ void edge_mlp(const unsigned char* __restrict__ wsb,
                         const int* __restrict__ src_idx,
                         const int* __restrict__ dst_idx,
                         const float* __restrict__ W2,
                         const float* __restrict__ b2p,
                         float* __restrict__ out) {
    const int tid  = threadIdx.x;
    const int c    = tid & 7;       // 16-byte slice of the 128-B row
    const int slot = tid >> 3;      // edge within block-pass (0..31)

    // W2 slice: 16 floats for cols c*16..c*16+15 (regs, reused 16 passes)
    floatx2 w2v[8];
#pragma unroll
    for (int i = 0; i < 8; ++i) w2v[i] = *(const floatx2*)(W2 + c * 16 + i * 2);
    const float b2v = b2p[0];

    const unsigned char* P8 = wsb + P8_OFF;
    const unsigned char* Q8 = wsb + Q8_OFF;
    const int ebase = blockIdx.x * 32 + slot;   // < 65536

#define LDIDX(K, SI, DI) do {                                        \
        int _e = ebase + (K) * ESTEP;                                \
        _e = _e < NE ? _e : NE - 1;                                  \
        SI = __builtin_nontemporal_load(src_idx + _e);               \
        DI = __builtin_nontemporal_load(dst_idx + _e);               \
    } while (0)

#define GATHER(SI, DI, PD, QD) do {                                  \
        PD = *(const uint4*)(P8 + (SI) * H + c * 16);                \
        QD = *(const uint4*)(Q8 + (DI) * H + c * 16);                \
    } while (0)

#define COMPUTE(K, PD, QD, MASKED) do {                              \
        floatx2 acc2 = {0.0f, 0.0f};                                 \
        const unsigned pw[4] = { PD.x, PD.y, PD.z, PD.w };           \
        const unsigned qw[4] = { QD.x, QD.y, QD.z, QD.w };           \
        _Pragma("unroll")                                            \
        for (int jw = 0; jw < 4; ++jw) {                             \
            floatx2 pl, ph, ql, qh;                                  \
            DECODE(pw[jw], qw[jw], pl, ph, ql, qh);                  \
            acc2 += relu2(pl + ql) * w2v[2 * jw];                    \
            acc2 += relu2(ph + qh) * w2v[2 * jw + 1];                \
        }                                                            \
        float acc = acc2.x + acc2.y;                                 \
        acc += __shfl_xor(acc, 1);                                   \
        acc += __shfl_xor(acc, 2);                                   \
        acc += __shfl_xor(acc, 4);                                   \
        const int _e = ebase + (K) * ESTEP;                          \
        if (c == 0 && (!(MASKED) || _e < NE)) {                      \
            const float r = fast_sigmoid(acc + b2v);                 \
            __builtin_nontemporal_store(r, out + _e);                \
        }                                                            \
    } while (0)

#if HW_FP8
#define DECODE(PW, QW, PL, PH, QL, QH) do {                          \
        PL = __builtin_amdgcn_cvt_pk_f32_fp8((int)(PW), false);      \
        PH = __builtin_amdgcn_cvt_pk_f32_fp8((int)(PW), true);       \
        QL = __builtin_amdgcn_cvt_pk_f32_fp8((int)(QW), false);      \
        QH = __builtin_amdgcn_cvt_pk_f32_fp8((int)(QW), true);       \
    } while (0)
#else
#define DECODE(PW, QW, PL, PH, QL, QH) do {                          \
        PL = { dec_e4m3((PW) & 0xff), dec_e4m3(((PW) >> 8) & 0xff) };  \
        PH = { dec_e4m3(((PW) >> 16) & 0xff), dec_e4m3((PW) >> 24) };  \
        QL = { dec_e4m3((QW) & 0xff), dec_e4m3(((QW) >> 8) & 0xff) };  \
        QH = { dec_e4m3(((QW) >> 16) & 0xff), dec_e4m3((QW) >> 24) };  \
    } while (0)
#endif

    // ---- prologue: rows(0,1) + idx(2,3) in flight ----
    int siA, diA, siB, diB, si2, di2, si3, di3;
    uint4 pdA, qdA, pdB, qdB;
    LDIDX(0, siA, diA);
    LDIDX(1, siB, diB);
    GATHER(siA, diA, pdA, qdA);
    GATHER(siB, diB, pdB, qdB);
    LDIDX(2, si2, di2);
    LDIDX(3, si3, di3);

    // ---- main: 7 iterations x 2 passes = k 0..13 (all full) ----
#pragma unroll 1
    for (int i = 0; i < 7; ++i) {
        const int k = 2 * i;
        uint4 pdC, qdC, pdD, qdD;
        GATHER(si2, di2, pdC, qdC);          // rows k+2
        GATHER(si3, di3, pdD, qdD);          // rows k+3
        LDIDX(k + 4, si2, di2);              // idx k+4 (clamped; k+4<=17)
        LDIDX(k + 5, si3, di3);              // idx k+5
        COMPUTE(k,     pdA, qdA, false);
        COMPUTE(k + 1, pdB, qdB, false);
        pdA = pdC; qdA = qdC; pdB = pdD; qdB = qdD;
    }

    // ---- epilogue: k=14 (full), k=15 (tail, store-masked) ----
    COMPUTE(14, pdA, qdA, false);
    COMPUTE(15, pdB, qdB, true);

#undef LDIDX
#undef GATHER
#undef COMPUTE
#undef DECODE
}

extern "C" void kernel_launch(void* const* d_in, const int* in_sizes, int n_in,
                              void* d_out, int out_size, void* d_ws, size_t ws_size,
                              hipStream_t stream) {
    const float* xin  = (const float*)d_in[0];
    const float* xcmp = (const float*)d_in[1];
    const int*   eidx = (const int*)d_in[2];    // [2,E]: first E src, next E dst
    const float* W1   = (const float*)d_in[3];
    const float* b1   = (const float*)d_in[4];
    const float* W2   = (const float*)d_in[5];
    const float* b2   = (const float*)d_in[6];
    float* out = (float*)d_out;
    unsigned char* wsb = (unsigned char*)d_ws;  // ~3.9 MB used

    hipLaunchKernelGGL(cvt_w,   dim3(128),           dim3(256), 0, stream, W1, wsb);
    hipLaunchKernelGGL(pq_gemm, dim3(PBLKS + QBLKS), dim3(256), 0, stream, xin, xcmp, b1, wsb);
    hipLaunchKernelGGL(edge_mlp, dim3(EGRID),        dim3(256), 0, stream,
                       wsb, eidx, eidx + NE, W2, b2, out);
}

// Round 8
// 109.710 us; speedup vs baseline: 1.3722x; 1.0045x over previous
//
#include <hip/hip_runtime.h>

// CompoundClassifier, round 15: fold cvt_w into pq_gemm (2 launches).
//   P = x_ing @ W1[:128], Q = x_cmp @ W1[128:] + b1  -> fp8 tables (1 B/el)
//   out[e] = sigmoid( relu(P[s]+Q[d]) . W2 + b2 )
// r14 post-mortem: cooperative launch silently never ran under graph capture
// (absmax 0.79 = zeroed out) -> grid.sync fusion is unusable here; reverted.
// Budget (r10/r12 measured): fill ~46 (harness, fixed) + edge ~28.6 + pq ~10-13
// + cvt ~2 + gaps. r15 deletes cvt_w and one kernel boundary: pq_gemm loads its
// W1 B-fragments directly from global (r9's code — passed bit-identical), cost
// now amortized over NSTRIP=4 strips at 470 blocks (~1/4 of r9's overhead).
// Edge kernel = r11/r13 winner, untouched.

#define H  128
#define NI 20000
#define NC 10000
#define NE 1000000

typedef _Float16 half8   __attribute__((ext_vector_type(8)));
typedef float    floatx2 __attribute__((ext_vector_type(2)));
typedef float    floatx4 __attribute__((ext_vector_type(4)));

// ws byte layout
#define P8_OFF    0
#define Q8_OFF    (NI * H)                    // 2,560,000
// total ws use: 3,840,000 B (P8 + Q8)

#define PB (NI / 16)   // 1250 strips of P
#define QB (NC / 16)   // 625 strips of Q
#define NSTRIP 4
#define PBLKS ((PB + NSTRIP - 1) / NSTRIP)    // 313
#define QBLKS ((QB + NSTRIP - 1) / NSTRIP)    // 157

// ---------- fp8 e4m3 helpers (HW path on gfx950; SW fallback for safety) ----
#if __has_builtin(__builtin_amdgcn_cvt_pk_f32_fp8) && __has_builtin(__builtin_amdgcn_cvt_pk_fp8_f32)
#define HW_FP8 1
#else
#define HW_FP8 0
__device__ inline unsigned char enc_e4m3(float x) {
    unsigned s = x < 0.0f ? 0x80u : 0u;
    float a = fminf(fabsf(x), 448.0f);
    if (a < 0.0009765625f) return (unsigned char)s;       // < 2^-10 -> 0
    int e; float m = frexpf(a, &e);                       // a = m*2^e, m in [0.5,1)
    int E = e + 6;                                        // biased exp
    if (E <= 0) {                                         // subnormal: f*2^-9
        int f = (int)rintf(a * 512.0f);
        if (f > 7) return (unsigned char)(s | 0x08);
        return (unsigned char)(s | f);
    }
    int f = (int)rintf((m * 2.0f - 1.0f) * 8.0f);
    if (f == 8) { f = 0; ++E; }
    if (E > 15 || (E == 15 && f > 6)) { E = 15; f = 6; }  // clamp to 448
    return (unsigned char)(s | (E << 3) | f);
}
__device__ inline float dec_e4m3(unsigned char b) {
    int E = (b >> 3) & 15, f = b & 7;
    float v = (E == 0) ? (float)f * 0.001953125f          // f * 2^-9
                       : (float)(8 + f) * exp2f((float)(E - 10));
    return (b & 0x80) ? -v : v;
}
#endif

__device__ inline floatx2 relu2(floatx2 v) {
#if __has_builtin(__builtin_elementwise_max)
    floatx2 z = {0.0f, 0.0f};
    return __builtin_elementwise_max(v, z);
#else
    floatx2 r = { fmaxf(v.x, 0.0f), fmaxf(v.y, 0.0f) };
    return r;
#endif
}

__device__ __forceinline__ float fast_sigmoid(float x) {
#if __has_builtin(__builtin_amdgcn_exp2f) && __has_builtin(__builtin_amdgcn_rcpf)
    const float t = __builtin_amdgcn_exp2f(-1.4426950408889634f * x);
    return __builtin_amdgcn_rcpf(1.0f + t);
#else
    return 1.0f / (1.0f + __expf(-x));
#endif
}

// ---------- P/Q precompute: direct W1 fragments, 4 strips/block ----------
__launch_bounds__(256)
__global__ void pq_gemm(const float* __restrict__ xin,
                        const float* __restrict__ xcmp,
                        const float* __restrict__ b1,
                        const float* __restrict__ W1,   // [256][128] row-major
                        unsigned char* __restrict__ wsb) {
    const int b    = blockIdx.x;
    const bool isQ = (b >= PBLKS);
    const int  sb  = isQ ? b - PBLKS : b;
    const int  s0  = sb * NSTRIP;                 // first strip of this block
    const int  smax = (isQ ? QB : PB) - 1;        // last valid strip
    const float* X = isQ ? xcmp : xin;
    unsigned char* OUT8 = wsb + (isQ ? Q8_OFF : P8_OFF);

    const int lane = threadIdx.x & 63;
    const int w    = threadIdx.x >> 6;
    const int quad = lane >> 4;
    const int m    = lane & 15;

    // B-fragments straight from W1, ONCE per block (amortized over 4 strips):
    //   bf[nt][ks][j] = W1[k][n], k = isQ*128 + ks*32 + quad*8 + j,
    //                             n = w*32 + nt*16 + m
    // Per 64-lane instr: 16 consecutive floats x 4 quads -> ~4 lines, L2-hot.
    half8 bf[2][4];
    float b1v[2];
#pragma unroll
    for (int nt = 0; nt < 2; ++nt) {
        const int n = w * 32 + nt * 16 + m;
#pragma unroll
        for (int ks = 0; ks < 4; ++ks) {
            const float* wp = W1 + (long)(isQ * 128 + ks * 32 + quad * 8) * H + n;
            half8 v;
#pragma unroll
            for (int j = 0; j < 8; ++j)
                v[j] = (_Float16)wp[j * H];
            bf[nt][ks] = v;
        }
        b1v[nt] = isQ ? b1[n] : 0.0f;
    }

    // A-fragment loader for strip S (clamped -> always in-bounds)
#define LOADA(S, AF) do {                                                \
        const int _s = (S) > smax ? smax : (S);                          \
        const float* xr = X + (long)(_s * 16 + m) * H + quad * 8;        \
        _Pragma("unroll")                                                \
        for (int ks = 0; ks < 4; ++ks) {                                 \
            float4 a = *(const float4*)(xr + ks * 32);                   \
            float4 c = *(const float4*)(xr + ks * 32 + 4);               \
            half8 v = { (_Float16)a.x, (_Float16)a.y, (_Float16)a.z,     \
                        (_Float16)a.w, (_Float16)c.x, (_Float16)c.y,     \
                        (_Float16)c.z, (_Float16)c.w };                  \
            AF[ks] = v;                                                  \
        }                                                                \
    } while (0)

#if HW_FP8
#define EMIT8(PTR, V) do {                                               \
        const unsigned _u = (unsigned)__builtin_amdgcn_cvt_pk_fp8_f32((V), (V), 0, false); \
        *(unsigned char*)(PTR) = (unsigned char)(_u & 0xff);             \
    } while (0)
#else
#define EMIT8(PTR, V) do { *(unsigned char*)(PTR) = enc_e4m3(V); } while (0)
#endif

    // compute + fp8 epilogue for strip S from fragments AF
#define STRIPC(S, AF) do {                                               \
        floatx4 acc[2] = { (floatx4)0.0f, (floatx4)0.0f };               \
        _Pragma("unroll")                                                \
        for (int ks = 0; ks < 4; ++ks)                                   \
            _Pragma("unroll")                                            \
            for (int nt = 0; nt < 2; ++nt)                               \
                acc[nt] = __builtin_amdgcn_mfma_f32_16x16x32_f16(        \
                              AF[ks], bf[nt][ks], acc[nt], 0, 0, 0);     \
        if ((S) <= smax) {                                               \
            const int rb = (S) * 16;                                     \
            _Pragma("unroll")                                            \
            for (int nt = 0; nt < 2; ++nt) {                             \
                const int col = w * 32 + nt * 16 + m;                    \
                _Pragma("unroll")                                        \
                for (int r = 0; r < 4; ++r) {                            \
                    const float v = acc[nt][r] + b1v[nt];                \
                    EMIT8(OUT8 + (rb + quad * 4 + r) * H + col, v);      \
                }                                                        \
            }                                                            \
        }                                                                \
    } while (0)

    // ping-pong A fragments: prefetch strip s+1 before computing strip s
    half8 afA[4], afB[4];
    LOADA(s0, afA);
    LOADA(s0 + 1, afB);
    STRIPC(s0,     afA);
    LOADA(s0 + 2, afA);
    STRIPC(s0 + 1, afB);
    LOADA(s0 + 3, afB);
    STRIPC(s0 + 2, afA);
    STRIPC(s0 + 3, afB);

#undef LOADA
#undef STRIPC
#undef EMIT8
}

// ---------- edge kernel: 8 lanes/edge, branch-free 16-pass, unroll-2 ----------
// (identical to r11/r13, best measured)
#define EGRID 2048
#define ESTEP (32 * EGRID)          // 65536 edges per device pass
// NE = 1,000,000 = 15 full passes (k=0..14) + tail pass k=15 (16,960 edges)

__launch_bounds__(256)
__global__ void edge_mlp(const unsigned char* __restrict__ wsb,
                         const int* __restrict__ src_idx,
                         const int* __restrict__ dst_idx,
                         const float* __restrict__ W2,
                         const float* __restrict__ b2p,
                         float* __restrict__ out) {
    const int tid  = threadIdx.x;
    const int c    = tid & 7;       // 16-byte slice of the 128-B row
    const int slot = tid >> 3;      // edge within block-pass (0..31)

    // W2 slice: 16 floats for cols c*16..c*16+15 (regs, reused 16 passes)
    floatx2 w2v[8];
#pragma unroll
    for (int i = 0; i < 8; ++i) w2v[i] = *(const floatx2*)(W2 + c * 16 + i * 2);
    const float b2v = b2p[0];

    const unsigned char* P8 = wsb + P8_OFF;
    const unsigned char* Q8 = wsb + Q8_OFF;
    const int ebase = blockIdx.x * 32 + slot;   // < 65536

#define LDIDX(K, SI, DI) do {                                        \
        int _e = ebase + (K) * ESTEP;                                \
        _e = _e < NE ? _e : NE - 1;                                  \
        SI = __builtin_nontemporal_load(src_idx + _e);               \
        DI = __builtin_nontemporal_load(dst_idx + _e);               \
    } while (0)

#define GATHER(SI, DI, PD, QD) do {                                  \
        PD = *(const uint4*)(P8 + (SI) * H + c * 16);                \
        QD = *(const uint4*)(Q8 + (DI) * H + c * 16);                \
    } while (0)

#if HW_FP8
#define DECODE(PW, QW, PL, PH, QL, QH) do {                          \
        PL = __builtin_amdgcn_cvt_pk_f32_fp8((int)(PW), false);      \
        PH = __builtin_amdgcn_cvt_pk_f32_fp8((int)(PW), true);       \
        QL = __builtin_amdgcn_cvt_pk_f32_fp8((int)(QW), false);      \
        QH = __builtin_amdgcn_cvt_pk_f32_fp8((int)(QW), true);       \
    } while (0)
#else
#define DECODE(PW, QW, PL, PH, QL, QH) do {                          \
        PL = { dec_e4m3((PW) & 0xff), dec_e4m3(((PW) >> 8) & 0xff) };  \
        PH = { dec_e4m3(((PW) >> 16) & 0xff), dec_e4m3((PW) >> 24) };  \
        QL = { dec_e4m3((QW) & 0xff), dec_e4m3(((QW) >> 8) & 0xff) };  \
        QH = { dec_e4m3(((QW) >> 16) & 0xff), dec_e4m3((QW) >> 24) };  \
    } while (0)
#endif

#define COMPUTE(K, PD, QD, MASKED) do {                              \
        floatx2 acc2 = {0.0f, 0.0f};                                 \
        const unsigned pw[4] = { PD.x, PD.y, PD.z, PD.w };           \
        const unsigned qw[4] = { QD.x, QD.y, QD.z, QD.w };           \
        _Pragma("unroll")                                            \
        for (int jw = 0; jw < 4; ++jw) {                             \
            floatx2 pl, ph, ql, qh;                                  \
            DECODE(pw[jw], qw[jw], pl, ph, ql, qh);                  \
            acc2 += relu2(pl + ql) * w2v[2 * jw];                    \
            acc2 += relu2(ph + qh) * w2v[2 * jw + 1];                \
        }                                                            \
        float acc = acc2.x + acc2.y;                                 \
        acc += __shfl_xor(acc, 1);                                   \
        acc += __shfl_xor(acc, 2);                                   \
        acc += __shfl_xor(acc, 4);                                   \
        const int _e = ebase + (K) * ESTEP;                          \
        if (c == 0 && (!(MASKED) || _e < NE)) {                      \
            const float r = fast_sigmoid(acc + b2v);                 \
            __builtin_nontemporal_store(r, out + _e);                \
        }                                                            \
    } while (0)

    // ---- prologue: rows(0,1) + idx(2,3) in flight ----
    int siA, diA, siB, diB, si2, di2, si3, di3;
    uint4 pdA, qdA, pdB, qdB;
    LDIDX(0, siA, diA);
    LDIDX(1, siB, diB);
    GATHER(siA, diA, pdA, qdA);
    GATHER(siB, diB, pdB, qdB);
    LDIDX(2, si2, di2);
    LDIDX(3, si3, di3);

    // ---- main: 7 iterations x 2 passes = k 0..13 (all full) ----
#pragma unroll 1
    for (int i = 0; i < 7; ++i) {
        const int k = 2 * i;
        uint4 pdC, qdC, pdD, qdD;
        GATHER(si2, di2, pdC, qdC);          // rows k+2
        GATHER(si3, di3, pdD, qdD);          // rows k+3
        LDIDX(k + 4, si2, di2);              // idx k+4 (clamped; k+4<=17)
        LDIDX(k + 5, si3, di3);              // idx k+5
        COMPUTE(k,     pdA, qdA, false);
        COMPUTE(k + 1, pdB, qdB, false);
        pdA = pdC; qdA = qdC; pdB = pdD; qdB = qdD;
    }

    // ---- epilogue: k=14 (full), k=15 (tail, store-masked) ----
    COMPUTE(14, pdA, qdA, false);
    COMPUTE(15, pdB, qdB, true);

#undef LDIDX
#undef GATHER
#undef COMPUTE
#undef DECODE
}

extern "C" void kernel_launch(void* const* d_in, const int* in_sizes, int n_in,
                              void* d_out, int out_size, void* d_ws, size_t ws_size,
                              hipStream_t stream) {
    const float* xin  = (const float*)d_in[0];
    const float* xcmp = (const float*)d_in[1];
    const int*   eidx = (const int*)d_in[2];    // [2,E]: first E src, next E dst
    const float* W1   = (const float*)d_in[3];
    const float* b1   = (const float*)d_in[4];
    const float* W2   = (const float*)d_in[5];
    const float* b2   = (const float*)d_in[6];
    float* out = (float*)d_out;
    unsigned char* wsb = (unsigned char*)d_ws;  // 3.84 MB used

    hipLaunchKernelGGL(pq_gemm, dim3(PBLKS + QBLKS), dim3(256), 0, stream,
                       xin, xcmp, b1, W1, wsb);
    hipLaunchKernelGGL(edge_mlp, dim3(EGRID), dim3(256), 0, stream,
                       wsb, eidx, eidx + NE, W2, b2, out);
}

// Round 10
// 107.750 us; speedup vs baseline: 1.3971x; 1.0182x over previous
//
#include <hip/hip_runtime.h>

// CompoundClassifier, round 17: r16 resubmit — DPP ctrl as template constant.
//   P = x_ing @ W1[:128], Q = x_cmp @ W1[128:] + b1  -> fp8 tables (1 B/el)
//   out[e] = sigmoid( relu(P[s]+Q[d]) . W2 + b2 )
// r16 failed to COMPILE: __builtin_amdgcn_update_dpp needs a constant-integer
// dpp_ctrl; passing via function arg broke. Fixed with template<int CTRL>.
// Theory unchanged: edge static count ~75 wave-insts/pass -> 7.6us issue floor,
// measured 28.6 -> likely latency-bound (rows only 1-2 passes ahead < L2 lat).
// (1) FULL 16-pass unroll, rows 4 passes ahead, idx 8 ahead (SSA regs, counted
// vmcnt); (2) DPP butterfly reduce (pure VALU) + unconditional sigmoid.

#define H  128
#define NI 20000
#define NC 10000
#define NE 1000000

typedef _Float16 half8   __attribute__((ext_vector_type(8)));
typedef float    floatx2 __attribute__((ext_vector_type(2)));
typedef float    floatx4 __attribute__((ext_vector_type(4)));

// ws byte layout
#define P8_OFF    0
#define Q8_OFF    (NI * H)                    // 2,560,000
// total ws use: 3,840,000 B (P8 + Q8)

#define PB (NI / 16)   // 1250 strips of P
#define QB (NC / 16)   // 625 strips of Q
#define NSTRIP 4
#define PBLKS ((PB + NSTRIP - 1) / NSTRIP)    // 313
#define QBLKS ((QB + NSTRIP - 1) / NSTRIP)    // 157

// ---------- fp8 e4m3 helpers (HW path on gfx950; SW fallback for safety) ----
#if __has_builtin(__builtin_amdgcn_cvt_pk_f32_fp8) && __has_builtin(__builtin_amdgcn_cvt_pk_fp8_f32)
#define HW_FP8 1
#else
#define HW_FP8 0
__device__ inline unsigned char enc_e4m3(float x) {
    unsigned s = x < 0.0f ? 0x80u : 0u;
    float a = fminf(fabsf(x), 448.0f);
    if (a < 0.0009765625f) return (unsigned char)s;       // < 2^-10 -> 0
    int e; float m = frexpf(a, &e);                       // a = m*2^e, m in [0.5,1)
    int E = e + 6;                                        // biased exp
    if (E <= 0) {                                         // subnormal: f*2^-9
        int f = (int)rintf(a * 512.0f);
        if (f > 7) return (unsigned char)(s | 0x08);
        return (unsigned char)(s | f);
    }
    int f = (int)rintf((m * 2.0f - 1.0f) * 8.0f);
    if (f == 8) { f = 0; ++E; }
    if (E > 15 || (E == 15 && f > 6)) { E = 15; f = 6; }  // clamp to 448
    return (unsigned char)(s | (E << 3) | f);
}
__device__ inline float dec_e4m3(unsigned char b) {
    int E = (b >> 3) & 15, f = b & 7;
    float v = (E == 0) ? (float)f * 0.001953125f          // f * 2^-9
                       : (float)(8 + f) * exp2f((float)(E - 10));
    return (b & 0x80) ? -v : v;
}
#endif

__device__ inline floatx2 relu2(floatx2 v) {
#if __has_builtin(__builtin_elementwise_max)
    floatx2 z = {0.0f, 0.0f};
    return __builtin_elementwise_max(v, z);
#else
    floatx2 r = { fmaxf(v.x, 0.0f), fmaxf(v.y, 0.0f) };
    return r;
#endif
}

__device__ __forceinline__ float fast_sigmoid(float x) {
#if __has_builtin(__builtin_amdgcn_exp2f) && __has_builtin(__builtin_amdgcn_rcpf)
    const float t = __builtin_amdgcn_exp2f(-1.4426950408889634f * x);
    return __builtin_amdgcn_rcpf(1.0f + t);
#else
    return 1.0f / (1.0f + __expf(-x));
#endif
}

// DPP-fused butterfly add over 8-lane groups (no LDS pipe, no lgkmcnt).
// CTRL must be a compile-time constant -> template parameter.
#if __has_builtin(__builtin_amdgcn_update_dpp)
template <int CTRL>
__device__ __forceinline__ float dpp_add(float x) {
    const int yi = __builtin_amdgcn_update_dpp(0, __float_as_int(x), CTRL, 0xf, 0xf, false);
    return x + __int_as_float(yi);
}
#define REDUCE8(ACC) do {                          \
        ACC = dpp_add<0xB1>(ACC);  /* quad_perm [1,0,3,2] : xor1 */        \
        ACC = dpp_add<0x4E>(ACC);  /* quad_perm [2,3,0,1] : xor2 */        \
        ACC = dpp_add<0x141>(ACC); /* row_half_mirror     : xor4 */        \
    } while (0)
#else
#define REDUCE8(ACC) do {                          \
        ACC += __shfl_xor(ACC, 1);                 \
        ACC += __shfl_xor(ACC, 2);                 \
        ACC += __shfl_xor(ACC, 4);                 \
    } while (0)
#endif

// ---------- P/Q precompute: direct W1 fragments, 4 strips/block (r15) -------
__launch_bounds__(256)
__global__ void pq_gemm(const float* __restrict__ xin,
                        const float* __restrict__ xcmp,
                        const float* __restrict__ b1,
                        const float* __restrict__ W1,   // [256][128] row-major
                        unsigned char* __restrict__ wsb) {
    const int b    = blockIdx.x;
    const bool isQ = (b >= PBLKS);
    const int  sb  = isQ ? b - PBLKS : b;
    const int  s0  = sb * NSTRIP;                 // first strip of this block
    const int  smax = (isQ ? QB : PB) - 1;        // last valid strip
    const float* X = isQ ? xcmp : xin;
    unsigned char* OUT8 = wsb + (isQ ? Q8_OFF : P8_OFF);

    const int lane = threadIdx.x & 63;
    const int w    = threadIdx.x >> 6;
    const int quad = lane >> 4;
    const int m    = lane & 15;

    // B-fragments straight from W1, ONCE per block (amortized over 4 strips)
    half8 bf[2][4];
    float b1v[2];
#pragma unroll
    for (int nt = 0; nt < 2; ++nt) {
        const int n = w * 32 + nt * 16 + m;
#pragma unroll
        for (int ks = 0; ks < 4; ++ks) {
            const float* wp = W1 + (long)(isQ * 128 + ks * 32 + quad * 8) * H + n;
            half8 v;
#pragma unroll
            for (int j = 0; j < 8; ++j)
                v[j] = (_Float16)wp[j * H];
            bf[nt][ks] = v;
        }
        b1v[nt] = isQ ? b1[n] : 0.0f;
    }

#define LOADA(S, AF) do {                                                \
        const int _s = (S) > smax ? smax : (S);                          \
        const float* xr = X + (long)(_s * 16 + m) * H + quad * 8;        \
        _Pragma("unroll")                                                \
        for (int ks = 0; ks < 4; ++ks) {                                 \
            float4 a = *(const float4*)(xr + ks * 32);                   \
            float4 c = *(const float4*)(xr + ks * 32 + 4);               \
            half8 v = { (_Float16)a.x, (_Float16)a.y, (_Float16)a.z,     \
                        (_Float16)a.w, (_Float16)c.x, (_Float16)c.y,     \
                        (_Float16)c.z, (_Float16)c.w };                  \
            AF[ks] = v;                                                  \
        }                                                                \
    } while (0)

#if HW_FP8
#define EMIT8(PTR, V) do {                                               \
        const unsigned _u = (unsigned)__builtin_amdgcn_cvt_pk_fp8_f32((V), (V), 0, false); \
        *(unsigned char*)(PTR) = (unsigned char)(_u & 0xff);             \
    } while (0)
#else
#define EMIT8(PTR, V) do { *(unsigned char*)(PTR) = enc_e4m3(V); } while (0)
#endif

#define STRIPC(S, AF) do {                                               \
        floatx4 acc[2] = { (floatx4)0.0f, (floatx4)0.0f };               \
        _Pragma("unroll")                                                \
        for (int ks = 0; ks < 4; ++ks)                                   \
            _Pragma("unroll")                                            \
            for (int nt = 0; nt < 2; ++nt)                               \
                acc[nt] = __builtin_amdgcn_mfma_f32_16x16x32_f16(        \
                              AF[ks], bf[nt][ks], acc[nt], 0, 0, 0);     \
        if ((S) <= smax) {                                               \
            const int rb = (S) * 16;                                     \
            _Pragma("unroll")                                            \
            for (int nt = 0; nt < 2; ++nt) {                             \
                const int col = w * 32 + nt * 16 + m;                    \
                _Pragma("unroll")                                        \
                for (int r = 0; r < 4; ++r) {                            \
                    const float v = acc[nt][r] + b1v[nt];                \
                    EMIT8(OUT8 + (rb + quad * 4 + r) * H + col, v);      \
                }                                                        \
            }                                                            \
        }                                                                \
    } while (0)

    half8 afA[4], afB[4];
    LOADA(s0, afA);
    LOADA(s0 + 1, afB);
    STRIPC(s0,     afA);
    LOADA(s0 + 2, afA);
    STRIPC(s0 + 1, afB);
    LOADA(s0 + 3, afB);
    STRIPC(s0 + 2, afA);
    STRIPC(s0 + 3, afB);

#undef LOADA
#undef STRIPC
#undef EMIT8
}

// ---------- edge kernel: 8 lanes/edge, FULL 16-pass unroll, depth-4 rows ----
#define EGRID 2048
#define ESTEP (32 * EGRID)          // 65536 edges per device pass
// NE = 1,000,000 = 15 full passes (k=0..14) + tail pass k=15 (16,960 edges)

__launch_bounds__(256)
__global__ void edge_mlp(const unsigned char* __restrict__ wsb,
                         const int* __restrict__ src_idx,
                         const int* __restrict__ dst_idx,
                         const float* __restrict__ W2,
                         const float* __restrict__ b2p,
                         float* __restrict__ out) {
    const int tid  = threadIdx.x;
    const int c    = tid & 7;       // 16-byte slice of the 128-B row
    const int slot = tid >> 3;      // edge within block-pass (0..31)

    // W2 slice: 16 floats for cols c*16..c*16+15 (regs, reused 16 passes)
    floatx2 w2v[8];
#pragma unroll
    for (int i = 0; i < 8; ++i) w2v[i] = *(const floatx2*)(W2 + c * 16 + i * 2);
    const float b2v = b2p[0];

    const unsigned char* P8 = wsb + P8_OFF;
    const unsigned char* Q8 = wsb + Q8_OFF;
    const int ebase = blockIdx.x * 32 + slot;   // < 65536

    int  si[16], di[16];
    uint4 pd[16], qd[16];

    // idx load: only k=15 can run past NE (clamped; its store is masked)
#define LDIDX(K) do {                                                \
        int _e = ebase + (K) * ESTEP;                                \
        if ((K) == 15) _e = _e < NE ? _e : NE - 1;                   \
        si[K] = __builtin_nontemporal_load(src_idx + _e);            \
        di[K] = __builtin_nontemporal_load(dst_idx + _e);            \
    } while (0)

#define ISSUE(K) do {                                                \
        pd[K] = *(const uint4*)(P8 + si[K] * H + c * 16);            \
        qd[K] = *(const uint4*)(Q8 + di[K] * H + c * 16);            \
    } while (0)

#if HW_FP8
#define DECODE(PW, QW, PL, PH, QL, QH) do {                          \
        PL = __builtin_amdgcn_cvt_pk_f32_fp8((int)(PW), false);      \
        PH = __builtin_amdgcn_cvt_pk_f32_fp8((int)(PW), true);       \
        QL = __builtin_amdgcn_cvt_pk_f32_fp8((int)(QW), false);      \
        QH = __builtin_amdgcn_cvt_pk_f32_fp8((int)(QW), true);       \
    } while (0)
#else
#define DECODE(PW, QW, PL, PH, QL, QH) do {                          \
        PL = { dec_e4m3((PW) & 0xff), dec_e4m3(((PW) >> 8) & 0xff) };  \
        PH = { dec_e4m3(((PW) >> 16) & 0xff), dec_e4m3((PW) >> 24) };  \
        QL = { dec_e4m3((QW) & 0xff), dec_e4m3(((QW) >> 8) & 0xff) };  \
        QH = { dec_e4m3(((QW) >> 16) & 0xff), dec_e4m3((QW) >> 24) };  \
    } while (0)
#endif

#define COMPUTE(K) do {                                              \
        floatx2 acc2 = {0.0f, 0.0f};                                 \
        const unsigned pw[4] = { pd[K].x, pd[K].y, pd[K].z, pd[K].w }; \
        const unsigned qw[4] = { qd[K].x, qd[K].y, qd[K].z, qd[K].w }; \
        _Pragma("unroll")                                            \
        for (int jw = 0; jw < 4; ++jw) {                             \
            floatx2 pl, ph, ql, qh;                                  \
            DECODE(pw[jw], qw[jw], pl, ph, ql, qh);                  \
            acc2 += relu2(pl + ql) * w2v[2 * jw];                    \
            acc2 += relu2(ph + qh) * w2v[2 * jw + 1];                \
        }                                                            \
        float acc = acc2.x + acc2.y;                                 \
        REDUCE8(acc);                                                \
        const float r = fast_sigmoid(acc + b2v);  /* all lanes (no divergence) */ \
        const int _e = ebase + (K) * ESTEP;                          \
        if (c == 0 && ((K) < 15 || _e < NE))                         \
            __builtin_nontemporal_store(r, out + _e);                \
    } while (0)

    // ---- software pipeline (fully unrolled; all indices compile-time) ----
    // idx 8 passes ahead, rows 4 passes ahead (~500cy + multi-wave overlap)
#pragma unroll
    for (int k = 0; k < 8; ++k) LDIDX(k);
#pragma unroll
    for (int k = 0; k < 4; ++k) ISSUE(k);
#pragma unroll
    for (int k = 0; k < 16; ++k) {
        if (k + 4 < 16) ISSUE(k + 4);
        if (k + 8 < 16) LDIDX(k + 8);
        COMPUTE(k);
    }

#undef LDIDX
#undef ISSUE
#undef COMPUTE
#undef DECODE
}

extern "C" void kernel_launch(void* const* d_in, const int* in_sizes, int n_in,
                              void* d_out, int out_size, void* d_ws, size_t ws_size,
                              hipStream_t stream) {
    const float* xin  = (const float*)d_in[0];
    const float* xcmp = (const float*)d_in[1];
    const int*   eidx = (const int*)d_in[2];    // [2,E]: first E src, next E dst
    const float* W1   = (const float*)d_in[3];
    const float* b1   = (const float*)d_in[4];
    const float* W2   = (const float*)d_in[5];
    const float* b2   = (const float*)d_in[6];
    float* out = (float*)d_out;
    unsigned char* wsb = (unsigned char*)d_ws;  // 3.84 MB used

    hipLaunchKernelGGL(pq_gemm, dim3(PBLKS + QBLKS), dim3(256), 0, stream,
                       xin, xcmp, b1, W1, wsb);
    hipLaunchKernelGGL(edge_mlp, dim3(EGRID), dim3(256), 0, stream,
                       wsb, eidx, eidx + NE, W2, b2, out);
}

// Round 11
// 106.968 us; speedup vs baseline: 1.4073x; 1.0073x over previous
//
#include <hip/hip_runtime.h>

// CompoundClassifier, round 18: f16 inner math in edge kernel (issue-rate fix).
//   P = x_ing @ W1[:128], Q = x_cmp @ W1[128:] + b1  -> fp8 tables (1 B/el)
//   out[e] = sigmoid( relu(P[s]+Q[d]) . W2 + b2 )
// r17 post-mortem: deep pipeline + DPP = only -2us -> edge is VALU-ISSUE-bound
// with a rate penalty: pk_*_f32 and cvt_pk_f32_fp8 are 64-bit/lane ops = 2x
// issue slots on SIMD-32. ~40 static insts/pass -> ~80 issue-equivalents,
// matching the measured ~19us VALU time (r10: VALUBusy 68% of 28.6us).
// r18: decode fp8->f16 (v_cvt_pk_f16_fp8, gfx950-new, 32-bit result = full
// rate), math in pk_f16, dot via v_dot2_f32_f16 (f32 accumulate). Halves the
// issue cost of decode+math. Fallback to the proven f32 path if builtins
// missing. Everything else (pipeline, DPP reduce, pq_gemm) unchanged.

#define H  128
#define NI 20000
#define NC 10000
#define NE 1000000

typedef _Float16 half8   __attribute__((ext_vector_type(8)));
typedef _Float16 half2   __attribute__((ext_vector_type(2)));
typedef float    floatx2 __attribute__((ext_vector_type(2)));
typedef float    floatx4 __attribute__((ext_vector_type(4)));

// ws byte layout
#define P8_OFF    0
#define Q8_OFF    (NI * H)                    // 2,560,000
// total ws use: 3,840,000 B (P8 + Q8)

#define PB (NI / 16)   // 1250 strips of P
#define QB (NC / 16)   // 625 strips of Q
#define NSTRIP 4
#define PBLKS ((PB + NSTRIP - 1) / NSTRIP)    // 313
#define QBLKS ((QB + NSTRIP - 1) / NSTRIP)    // 157

// ---------- fp8 e4m3 helpers (HW path on gfx950; SW fallback for safety) ----
#if __has_builtin(__builtin_amdgcn_cvt_pk_f32_fp8) && __has_builtin(__builtin_amdgcn_cvt_pk_fp8_f32)
#define HW_FP8 1
#else
#define HW_FP8 0
__device__ inline unsigned char enc_e4m3(float x) {
    unsigned s = x < 0.0f ? 0x80u : 0u;
    float a = fminf(fabsf(x), 448.0f);
    if (a < 0.0009765625f) return (unsigned char)s;       // < 2^-10 -> 0
    int e; float m = frexpf(a, &e);                       // a = m*2^e, m in [0.5,1)
    int E = e + 6;                                        // biased exp
    if (E <= 0) {                                         // subnormal: f*2^-9
        int f = (int)rintf(a * 512.0f);
        if (f > 7) return (unsigned char)(s | 0x08);
        return (unsigned char)(s | f);
    }
    int f = (int)rintf((m * 2.0f - 1.0f) * 8.0f);
    if (f == 8) { f = 0; ++E; }
    if (E > 15 || (E == 15 && f > 6)) { E = 15; f = 6; }  // clamp to 448
    return (unsigned char)(s | (E << 3) | f);
}
__device__ inline float dec_e4m3(unsigned char b) {
    int E = (b >> 3) & 15, f = b & 7;
    float v = (E == 0) ? (float)f * 0.001953125f          // f * 2^-9
                       : (float)(8 + f) * exp2f((float)(E - 10));
    return (b & 0x80) ? -v : v;
}
#endif

// f16 fast path: fp8->f16 packed decode + dot2 f16 MAC with f32 accumulate
#if HW_FP8 && __has_builtin(__builtin_amdgcn_cvt_pk_f16_fp8) && __has_builtin(__builtin_amdgcn_fdot2)
#define HW_F16 1
__device__ __forceinline__ half2 dec2h(short s) {
    auto t = __builtin_amdgcn_cvt_pk_f16_fp8(s);
    half2 r; __builtin_memcpy(&r, &t, sizeof(r)); return r;
}
__device__ __forceinline__ half2 hrelu2(half2 v) {
#if __has_builtin(__builtin_elementwise_max)
    half2 z = {(_Float16)0.0f, (_Float16)0.0f};
    return __builtin_elementwise_max(v, z);
#else
    half2 r = { v.x > (_Float16)0.0f ? v.x : (_Float16)0.0f,
                v.y > (_Float16)0.0f ? v.y : (_Float16)0.0f };
    return r;
#endif
}
#else
#define HW_F16 0
#endif

__device__ inline floatx2 relu2(floatx2 v) {
#if __has_builtin(__builtin_elementwise_max)
    floatx2 z = {0.0f, 0.0f};
    return __builtin_elementwise_max(v, z);
#else
    floatx2 r = { fmaxf(v.x, 0.0f), fmaxf(v.y, 0.0f) };
    return r;
#endif
}

__device__ __forceinline__ float fast_sigmoid(float x) {
#if __has_builtin(__builtin_amdgcn_exp2f) && __has_builtin(__builtin_amdgcn_rcpf)
    const float t = __builtin_amdgcn_exp2f(-1.4426950408889634f * x);
    return __builtin_amdgcn_rcpf(1.0f + t);
#else
    return 1.0f / (1.0f + __expf(-x));
#endif
}

// DPP-fused butterfly add over 8-lane groups (no LDS pipe, no lgkmcnt)
#if __has_builtin(__builtin_amdgcn_update_dpp)
template <int CTRL>
__device__ __forceinline__ float dpp_add(float x) {
    const int yi = __builtin_amdgcn_update_dpp(0, __float_as_int(x), CTRL, 0xf, 0xf, false);
    return x + __int_as_float(yi);
}
#define REDUCE8(ACC) do {                          \
        ACC = dpp_add<0xB1>(ACC);  /* quad_perm [1,0,3,2] : xor1 */        \
        ACC = dpp_add<0x4E>(ACC);  /* quad_perm [2,3,0,1] : xor2 */        \
        ACC = dpp_add<0x141>(ACC); /* row_half_mirror     : xor4 */        \
    } while (0)
#else
#define REDUCE8(ACC) do {                          \
        ACC += __shfl_xor(ACC, 1);                 \
        ACC += __shfl_xor(ACC, 2);                 \
        ACC += __shfl_xor(ACC, 4);                 \
    } while (0)
#endif

// ---------- P/Q precompute: direct W1 fragments, 4 strips/block (r15) -------
__launch_bounds__(256)
__global__ void pq_gemm(const float* __restrict__ xin,
                        const float* __restrict__ xcmp,
                        const float* __restrict__ b1,
                        const float* __restrict__ W1,   // [256][128] row-major
                        unsigned char* __restrict__ wsb) {
    const int b    = blockIdx.x;
    const bool isQ = (b >= PBLKS);
    const int  sb  = isQ ? b - PBLKS : b;
    const int  s0  = sb * NSTRIP;                 // first strip of this block
    const int  smax = (isQ ? QB : PB) - 1;        // last valid strip
    const float* X = isQ ? xcmp : xin;
    unsigned char* OUT8 = wsb + (isQ ? Q8_OFF : P8_OFF);

    const int lane = threadIdx.x & 63;
    const int w    = threadIdx.x >> 6;
    const int quad = lane >> 4;
    const int m    = lane & 15;

    // B-fragments straight from W1, ONCE per block (amortized over 4 strips)
    half8 bf[2][4];
    float b1v[2];
#pragma unroll
    for (int nt = 0; nt < 2; ++nt) {
        const int n = w * 32 + nt * 16 + m;
#pragma unroll
        for (int ks = 0; ks < 4; ++ks) {
            const float* wp = W1 + (long)(isQ * 128 + ks * 32 + quad * 8) * H + n;
            half8 v;
#pragma unroll
            for (int j = 0; j < 8; ++j)
                v[j] = (_Float16)wp[j * H];
            bf[nt][ks] = v;
        }
        b1v[nt] = isQ ? b1[n] : 0.0f;
    }

#define LOADA(S, AF) do {                                                \
        const int _s = (S) > smax ? smax : (S);                          \
        const float* xr = X + (long)(_s * 16 + m) * H + quad * 8;        \
        _Pragma("unroll")                                                \
        for (int ks = 0; ks < 4; ++ks) {                                 \
            float4 a = *(const float4*)(xr + ks * 32);                   \
            float4 c = *(const float4*)(xr + ks * 32 + 4);               \
            half8 v = { (_Float16)a.x, (_Float16)a.y, (_Float16)a.z,     \
                        (_Float16)a.w, (_Float16)c.x, (_Float16)c.y,     \
                        (_Float16)c.z, (_Float16)c.w };                  \
            AF[ks] = v;                                                  \
        }                                                                \
    } while (0)

#if HW_FP8
#define EMIT8(PTR, V) do {                                               \
        const unsigned _u = (unsigned)__builtin_amdgcn_cvt_pk_fp8_f32((V), (V), 0, false); \
        *(unsigned char*)(PTR) = (unsigned char)(_u & 0xff);             \
    } while (0)
#else
#define EMIT8(PTR, V) do { *(unsigned char*)(PTR) = enc_e4m3(V); } while (0)
#endif

#define STRIPC(S, AF) do {                                               \
        floatx4 acc[2] = { (floatx4)0.0f, (floatx4)0.0f };               \
        _Pragma("unroll")                                                \
        for (int ks = 0; ks < 4; ++ks)                                   \
            _Pragma("unroll")                                            \
            for (int nt = 0; nt < 2; ++nt)                               \
                acc[nt] = __builtin_amdgcn_mfma_f32_16x16x32_f16(        \
                              AF[ks], bf[nt][ks], acc[nt], 0, 0, 0);     \
        if ((S) <= smax) {                                               \
            const int rb = (S) * 16;                                     \
            _Pragma("unroll")                                            \
            for (int nt = 0; nt < 2; ++nt) {                             \
                const int col = w * 32 + nt * 16 + m;                    \
                _Pragma("unroll")                                        \
                for (int r = 0; r < 4; ++r) {                            \
                    const float v = acc[nt][r] + b1v[nt];                \
                    EMIT8(OUT8 + (rb + quad * 4 + r) * H + col, v);      \
                }                                                        \
            }                                                            \
        }                                                                \
    } while (0)

    half8 afA[4], afB[4];
    LOADA(s0, afA);
    LOADA(s0 + 1, afB);
    STRIPC(s0,     afA);
    LOADA(s0 + 2, afA);
    STRIPC(s0 + 1, afB);
    LOADA(s0 + 3, afB);
    STRIPC(s0 + 2, afA);
    STRIPC(s0 + 3, afB);

#undef LOADA
#undef STRIPC
#undef EMIT8
}

// ---------- edge kernel: 8 lanes/edge, FULL 16-pass unroll, f16 inner math --
#define EGRID 2048
#define ESTEP (32 * EGRID)          // 65536 edges per device pass
// NE = 1,000,000 = 15 full passes (k=0..14) + tail pass k=15 (16,960 edges)

__launch_bounds__(256)
__global__ void edge_mlp(const unsigned char* __restrict__ wsb,
                         const int* __restrict__ src_idx,
                         const int* __restrict__ dst_idx,
                         const float* __restrict__ W2,
                         const float* __restrict__ b2p,
                         float* __restrict__ out) {
    const int tid  = threadIdx.x;
    const int c    = tid & 7;       // 16-byte slice of the 128-B row
    const int slot = tid >> 3;      // edge within block-pass (0..31)

    // W2 slice: 16 coefficients for cols c*16..c*16+15
#if HW_F16
    half2 w2h[8];
#pragma unroll
    for (int i = 0; i < 8; ++i) {
        floatx2 f = *(const floatx2*)(W2 + c * 16 + i * 2);
        half2 h = { (_Float16)f.x, (_Float16)f.y };
        w2h[i] = h;
    }
#else
    floatx2 w2v[8];
#pragma unroll
    for (int i = 0; i < 8; ++i) w2v[i] = *(const floatx2*)(W2 + c * 16 + i * 2);
#endif
    const float b2v = b2p[0];

    const unsigned char* P8 = wsb + P8_OFF;
    const unsigned char* Q8 = wsb + Q8_OFF;
    const int ebase = blockIdx.x * 32 + slot;   // < 65536

    int  si[16], di[16];
    uint4 pd[16], qd[16];

    // idx load: only k=15 can run past NE (clamped; its store is masked)
#define LDIDX(K) do {                                                \
        int _e = ebase + (K) * ESTEP;                                \
        if ((K) == 15) _e = _e < NE ? _e : NE - 1;                   \
        si[K] = __builtin_nontemporal_load(src_idx + _e);            \
        di[K] = __builtin_nontemporal_load(dst_idx + _e);            \
    } while (0)

#define ISSUE(K) do {                                                \
        pd[K] = *(const uint4*)(P8 + si[K] * H + c * 16);            \
        qd[K] = *(const uint4*)(Q8 + di[K] * H + c * 16);            \
    } while (0)

#if HW_F16
    // f16 path: 4 dec + 2 pk_add + 2 pk_max + 2 fdot2 per word, all full-rate
#define INNER(PW, QW, JW, ACC) do {                                  \
        half2 pl = dec2h((short)(PW));                               \
        half2 ph = dec2h((short)((PW) >> 16));                       \
        half2 ql = dec2h((short)(QW));                               \
        half2 qh = dec2h((short)((QW) >> 16));                       \
        half2 hl = hrelu2(pl + ql);                                  \
        half2 hh = hrelu2(ph + qh);                                  \
        ACC = __builtin_amdgcn_fdot2(hl, w2h[2 * (JW)], ACC, false); \
        ACC = __builtin_amdgcn_fdot2(hh, w2h[2 * (JW) + 1], ACC, false); \
    } while (0)
#define COMPUTE(K) do {                                              \
        float acc = 0.0f;                                            \
        const unsigned pw[4] = { pd[K].x, pd[K].y, pd[K].z, pd[K].w }; \
        const unsigned qw[4] = { qd[K].x, qd[K].y, qd[K].z, qd[K].w }; \
        _Pragma("unroll")                                            \
        for (int jw = 0; jw < 4; ++jw)                               \
            INNER(pw[jw], qw[jw], jw, acc);                          \
        REDUCE8(acc);                                                \
        const float r = fast_sigmoid(acc + b2v);                     \
        const int _e = ebase + (K) * ESTEP;                          \
        if (c == 0 && ((K) < 15 || _e < NE))                         \
            __builtin_nontemporal_store(r, out + _e);                \
    } while (0)
#else
    // f32 fallback (proven r17 path)
#if HW_FP8
#define DECODE(PW, QW, PL, PH, QL, QH) do {                          \
        PL = __builtin_amdgcn_cvt_pk_f32_fp8((int)(PW), false);      \
        PH = __builtin_amdgcn_cvt_pk_f32_fp8((int)(PW), true);       \
        QL = __builtin_amdgcn_cvt_pk_f32_fp8((int)(QW), false);      \
        QH = __builtin_amdgcn_cvt_pk_f32_fp8((int)(QW), true);       \
    } while (0)
#else
#define DECODE(PW, QW, PL, PH, QL, QH) do {                          \
        PL = { dec_e4m3((PW) & 0xff), dec_e4m3(((PW) >> 8) & 0xff) };  \
        PH = { dec_e4m3(((PW) >> 16) & 0xff), dec_e4m3((PW) >> 24) };  \
        QL = { dec_e4m3((QW) & 0xff), dec_e4m3(((QW) >> 8) & 0xff) };  \
        QH = { dec_e4m3(((QW) >> 16) & 0xff), dec_e4m3((QW) >> 24) };  \
    } while (0)
#endif
#define COMPUTE(K) do {                                              \
        floatx2 acc2 = {0.0f, 0.0f};                                 \
        const unsigned pw[4] = { pd[K].x, pd[K].y, pd[K].z, pd[K].w }; \
        const unsigned qw[4] = { qd[K].x, qd[K].y, qd[K].z, qd[K].w }; \
        _Pragma("unroll")                                            \
        for (int jw = 0; jw < 4; ++jw) {                             \
            floatx2 pl, ph, ql, qh;                                  \
            DECODE(pw[jw], qw[jw], pl, ph, ql, qh);                  \
            acc2 += relu2(pl + ql) * w2v[2 * jw];                    \
            acc2 += relu2(ph + qh) * w2v[2 * jw + 1];                \
        }                                                            \
        float acc = acc2.x + acc2.y;                                 \
        REDUCE8(acc);                                                \
        const float r = fast_sigmoid(acc + b2v);                     \
        const int _e = ebase + (K) * ESTEP;                          \
        if (c == 0 && ((K) < 15 || _e < NE))                         \
            __builtin_nontemporal_store(r, out + _e);                \
    } while (0)
#endif

    // ---- software pipeline (fully unrolled; all indices compile-time) ----
    // idx 8 passes ahead, rows 4 passes ahead (~500cy + multi-wave overlap)
#pragma unroll
    for (int k = 0; k < 8; ++k) LDIDX(k);
#pragma unroll
    for (int k = 0; k < 4; ++k) ISSUE(k);
#pragma unroll
    for (int k = 0; k < 16; ++k) {
        if (k + 4 < 16) ISSUE(k + 4);
        if (k + 8 < 16) LDIDX(k + 8);
        COMPUTE(k);
    }

#undef LDIDX
#undef ISSUE
#undef COMPUTE
}

extern "C" void kernel_launch(void* const* d_in, const int* in_sizes, int n_in,
                              void* d_out, int out_size, void* d_ws, size_t ws_size,
                              hipStream_t stream) {
    const float* xin  = (const float*)d_in[0];
    const float* xcmp = (const float*)d_in[1];
    const int*   eidx = (const int*)d_in[2];    // [2,E]: first E src, next E dst
    const float* W1   = (const float*)d_in[3];
    const float* b1   = (const float*)d_in[4];
    const float* W2   = (const float*)d_in[5];
    const float* b2   = (const float*)d_in[6];
    float* out = (float*)d_out;
    unsigned char* wsb = (unsigned char*)d_ws;  // 3.84 MB used

    hipLaunchKernelGGL(pq_gemm, dim3(PBLKS + QBLKS), dim3(256), 0, stream,
                       xin, xcmp, b1, W1, wsb);
    hipLaunchKernelGGL(edge_mlp, dim3(EGRID), dim3(256), 0, stream,
                       wsb, eidx, eidx + NE, W2, b2, out);
}